// Round 12
// baseline (478.393 us; speedup 1.0000x reference)
//
#include <hip/hip_runtime.h>
#include <hip/hip_bf16.h>
#include <math.h>

// Problem constants (B=2, L=1024, d_model=1024, d_inner=2048)
constexpr int Bb  = 2;
constexpr int Ls  = 1024;
constexpr int DM  = 1024;   // d_model
constexpr int DI  = 2048;   // d_inner
constexpr int DXZ = 4096;   // 2*d_inner
constexpr int DXD = 96;     // dt_rank + 2*d_state
constexpr int DTR = 64;     // dt_rank
constexpr int DST = 16;     // d_state
constexpr int NCH = 8;      // scan chunks (measured: 8 beats 16)
constexpr int CHL = 128;    // chunk length (NCH*CHL == Ls)
constexpr int ML  = Bb * Ls;   // 2048 rows total

typedef __attribute__((ext_vector_type(8))) short bf16x8;
typedef __attribute__((ext_vector_type(4))) float f32x4;

__device__ __forceinline__ float sigmoidf_(float v) {
    return 1.0f / (1.0f + __expf(-v));
}

// pack two fp32 -> one dword of 2x bf16 (RTNE)
__device__ __forceinline__ int pk_bf16(float lo, float hi) {
    unsigned int ul = __float_as_uint(lo);
    ul += 0x7fffu + ((ul >> 16) & 1u);
    unsigned int uh = __float_as_uint(hi);
    uh += 0x7fffu + ((uh >> 16) & 1u);
    return (int)((ul >> 16) | (uh & 0xffff0000u));
}

// DPP-based sum over each aligned 16-lane group (4 VALU adds, no DS ops).
template <int CTRL>
__device__ __forceinline__ float dpp_add_(float v) {
    int t = __builtin_amdgcn_update_dpp(
        0, __float_as_int(v), CTRL, 0xF, 0xF, true);
    return v + __int_as_float(t);
}
__device__ __forceinline__ float red16_(float p) {
    p = dpp_add_<0xB1>(p);   // quad_perm(1,0,3,2)  : + lane^1
    p = dpp_add_<0x4E>(p);   // quad_perm(2,3,0,1)  : + lane^2
    p = dpp_add_<0x141>(p);  // row_half_mirror     : + other quad in 8
    p = dpp_add_<0x140>(p);  // row_mirror          : + other 8 in 16
    return p;                // all 16 lanes hold the group sum
}

// XOR-swizzled LDS chunk address: tile is [rows][4 chunks of 8 bf16].
__device__ __forceinline__ int swz(int row, int chunk) {
    return (((row << 2) + chunk) ^ (row & 7)) << 3;
}

// ---------------------------------------------------------------------------
// fp32 -> bf16 elementwise convert (4 elems/thread)
// ---------------------------------------------------------------------------
__global__ __launch_bounds__(256) void cvt_bf16_kernel(
    const float* __restrict__ in, unsigned short* __restrict__ out, int n4)
{
    const int i = blockIdx.x * 256 + threadIdx.x;
    if (i >= n4) return;
    const float4 v = *(const float4*)(in + (size_t)i * 4);
    *(int2*)(out + (size_t)i * 4) =
        make_int2(pk_bf16(v.x, v.y), pk_bf16(v.z, v.w));
}

// ---------------------------------------------------------------------------
// bf16 x bf16 MFMA GEMM: C[M,N] = A[M,K] @ W[N,K]^T, both bf16 row-major.
// Tile 128 x BNT (BNT = 64 or 128), 4 waves, BK=32.
// M%128==0, N%BNT==0, K%32==0.
// SPLIT==1: cols < DI -> C plain; cols >= DI -> C2 with silu applied.
// Split-K via blockIdx.z: A += z*za, W += z*zw, C += z*zc; pass K = Kc.
// ---------------------------------------------------------------------------
template <int SPLIT, int BNT>
__global__ __launch_bounds__(256) void gemm_bf16bf16(
    const unsigned short* __restrict__ A, int lda,
    const unsigned short* __restrict__ W, int ldw,
    float* __restrict__ C, float* __restrict__ C2, int ldc, int K,
    int za, int zw, long zc)
{
    constexpr int NACC = BNT / 32;           // wave col-frags (2 or 4)
    __shared__ __align__(16) unsigned short As[128 * 32];
    __shared__ __align__(16) unsigned short Ws[BNT * 32];

    const int tid  = threadIdx.x;
    const int lane = tid & 63;
    const int wave = tid >> 6;
    const int bm = blockIdx.y * 128;
    const int bn = blockIdx.x * BNT;
    const int z  = blockIdx.z;
    C += (size_t)z * zc;

    // A staging: thread t -> row t>>1, chunks (t&1)*2, +1  (2 int4 loads)
    const int srow = tid >> 1;
    const int cb   = (tid & 1) * 2;
    const unsigned short* Ag = A + (size_t)z * za
        + (size_t)(bm + srow) * lda + cb * 8;
    const int ia0 = swz(srow, cb);
    const int ia1 = swz(srow, cb + 1);

    // W staging
    const int srW = (BNT == 128) ? (tid >> 1) : (tid >> 2);
    const int cbW = (BNT == 128) ? (tid & 1) * 2 : (tid & 3);
    const unsigned short* Wg = W + (size_t)z * zw
        + (size_t)(bn + srW) * ldw + cbW * 8;
    const int iw0 = swz(srW, cbW);
    const int iw1 = (BNT == 128) ? swz(srW, cbW + 1) : 0;

    const int wr = (wave >> 1) * 64;
    const int wc = (wave & 1) * (BNT / 2);
    const int fr = lane & 15;
    const int fq = lane >> 4;

    f32x4 acc[4][NACC];
#pragma unroll
    for (int m = 0; m < 4; ++m)
#pragma unroll
        for (int n = 0; n < NACC; ++n) acc[m][n] = (f32x4){0.f, 0.f, 0.f, 0.f};

    for (int k0 = 0; k0 < K; k0 += 32) {
        const int4 pa0 = *(const int4*)(Ag + k0);
        const int4 pa1 = *(const int4*)(Ag + k0 + 8);
        const int4 pw0 = *(const int4*)(Wg + k0);
        int4 pw1;
        if (BNT == 128) pw1 = *(const int4*)(Wg + k0 + 8);

        __syncthreads();
        *(int4*)(As + ia0) = pa0;
        *(int4*)(As + ia1) = pa1;
        *(int4*)(Ws + iw0) = pw0;
        if (BNT == 128) *(int4*)(Ws + iw1) = pw1;
        __syncthreads();

        bf16x8 af[4], bfv[NACC];
#pragma unroll
        for (int m = 0; m < 4; ++m)
            af[m] = *(const bf16x8*)(As + swz(wr + m * 16 + fr, fq));
#pragma unroll
        for (int n = 0; n < NACC; ++n)
            bfv[n] = *(const bf16x8*)(Ws + swz(wc + n * 16 + fr, fq));
#pragma unroll
        for (int m = 0; m < 4; ++m)
#pragma unroll
            for (int n = 0; n < NACC; ++n)
                acc[m][n] = __builtin_amdgcn_mfma_f32_16x16x32_bf16(
                    af[m], bfv[n], acc[m][n], 0, 0, 0);
    }

#pragma unroll
    for (int m = 0; m < 4; ++m)
#pragma unroll
        for (int n = 0; n < NACC; ++n) {
            const int col = bn + wc + n * 16 + fr;
#pragma unroll
            for (int j = 0; j < 4; ++j) {
                const int row = bm + wr + m * 16 + fq * 4 + j;
                const float v = acc[m][n][j];
                if (SPLIT) {
                    if (col < DI) {
                        C[(size_t)row * ldc + col] = v;
                    } else {
                        C2[(size_t)row * ldc + (col - DI)] = v * sigmoidf_(v);
                    }
                } else {
                    C[(size_t)row * ldc + col] = v;
                }
            }
        }
}

// ---------------------------------------------------------------------------
// reduce 4 split-K partials -> out (float4 vectorized)
// ---------------------------------------------------------------------------
__global__ __launch_bounds__(256) void reduce4_kernel(
    const float* __restrict__ part, float* __restrict__ out, int n4)
{
    const int i = blockIdx.x * 256 + threadIdx.x;
    if (i >= n4) return;
    const size_t stride = (size_t)ML * DM;
    float4 a = *(const float4*)(part + (size_t)i * 4);
    const float4 b = *(const float4*)(part + stride + (size_t)i * 4);
    const float4 c = *(const float4*)(part + 2 * stride + (size_t)i * 4);
    const float4 d = *(const float4*)(part + 3 * stride + (size_t)i * 4);
    a.x += b.x + c.x + d.x;
    a.y += b.y + c.y + d.y;
    a.z += b.z + c.z + d.z;
    a.w += b.w + c.w + d.w;
    *(float4*)(out + (size_t)i * 4) = a;
}

// ---------------------------------------------------------------------------
// Generic fp32 GEMM: C[M,N] = A[M,K] @ W[N,K]^T.
// ATRANS==1: A is stored transposed [K][M].
// Split-K via blockIdx.z: A += z*za, W += z*zw, C += z*zc.
// EPI==2: C = softplus(C + bias[row]).
// ---------------------------------------------------------------------------
template <int EPI, int ATRANS>
__global__ __launch_bounds__(256) void gemm_nt(
    const float* __restrict__ A, int lda,
    const float* __restrict__ W, int ldw,
    float* __restrict__ C, int ldc,
    int N, int K, const float* __restrict__ bias, int za, int zw, int zc)
{
    A += (size_t)blockIdx.z * za;
    W += (size_t)blockIdx.z * zw;
    C += (size_t)blockIdx.z * zc;

    __shared__ float Asl[16][132];
    __shared__ float Wsl[16][132];

    const int tid = threadIdx.x;
    const int tx = tid & 15;
    const int ty = tid >> 4;
    const int bm = blockIdx.y * 128;
    const int bn = blockIdx.x * 128;

    const int lr = tid >> 1;
    const int lk = (tid & 1) * 8;
    const int krow = tid >> 4;          // ATRANS staging map
    const int mseg = (tid & 15) * 8;

    float acc[8][8];
#pragma unroll
    for (int i = 0; i < 8; ++i)
#pragma unroll
        for (int j = 0; j < 8; ++j) acc[i][j] = 0.0f;

    const float* Ap = ATRANS
        ? A + (size_t)krow * lda + bm + mseg
        : A + (size_t)(bm + lr) * lda + lk;
    const float* Wp = W + (size_t)(bn + lr) * ldw + lk;
    const bool wok = (bn + lr) < N;
    const float4 f4z = make_float4(0.f, 0.f, 0.f, 0.f);

    for (int k0 = 0; k0 < K; k0 += 16) {
        float4 av0, av1;
        if (ATRANS) {
            av0 = *(const float4*)(Ap + (size_t)k0 * lda);
            av1 = *(const float4*)(Ap + (size_t)k0 * lda + 4);
        } else {
            av0 = *(const float4*)(Ap + k0);
            av1 = *(const float4*)(Ap + k0 + 4);
        }
        const float4 wv0 = wok ? *(const float4*)(Wp + k0)     : f4z;
        const float4 wv1 = wok ? *(const float4*)(Wp + k0 + 4) : f4z;

        __syncthreads();
        if (ATRANS) {
            *(float4*)&Asl[krow][mseg]     = av0;
            *(float4*)&Asl[krow][mseg + 4] = av1;
        } else {
            Asl[lk + 0][lr] = av0.x; Asl[lk + 1][lr] = av0.y;
            Asl[lk + 2][lr] = av0.z; Asl[lk + 3][lr] = av0.w;
            Asl[lk + 4][lr] = av1.x; Asl[lk + 5][lr] = av1.y;
            Asl[lk + 6][lr] = av1.z; Asl[lk + 7][lr] = av1.w;
        }
        Wsl[lk + 0][lr] = wv0.x; Wsl[lk + 1][lr] = wv0.y;
        Wsl[lk + 2][lr] = wv0.z; Wsl[lk + 3][lr] = wv0.w;
        Wsl[lk + 4][lr] = wv1.x; Wsl[lk + 5][lr] = wv1.y;
        Wsl[lk + 6][lr] = wv1.z; Wsl[lk + 7][lr] = wv1.w;
        __syncthreads();

#pragma unroll
        for (int k = 0; k < 16; ++k) {
            const float4 a0 = *(const float4*)&Asl[k][(ty << 2)];
            const float4 a1 = *(const float4*)&Asl[k][64 + (ty << 2)];
            const float4 b0 = *(const float4*)&Wsl[k][(tx << 2)];
            const float4 b1 = *(const float4*)&Wsl[k][64 + (tx << 2)];
            const float ar[8] = {a0.x, a0.y, a0.z, a0.w, a1.x, a1.y, a1.z, a1.w};
            const float br[8] = {b0.x, b0.y, b0.z, b0.w, b1.x, b1.y, b1.z, b1.w};
#pragma unroll
            for (int i = 0; i < 8; ++i)
#pragma unroll
                for (int j = 0; j < 8; ++j)
                    acc[i][j] = fmaf(ar[i], br[j], acc[i][j]);
        }
    }

#pragma unroll
    for (int i = 0; i < 8; ++i) {
        const int row = bm + ((i & 4) << 4) + (ty << 2) + (i & 3);
#pragma unroll
        for (int j = 0; j < 8; ++j) {
            const int col = bn + ((j & 4) << 4) + (tx << 2) + (j & 3);
            if (col < N) {
                float v = acc[i][j];
                if (EPI == 2) {
                    v += bias[row];
                    v = (v > 20.f) ? v : log1pf(__expf(v));
                }
                C[(size_t)row * ldc + col] = v;
            }
        }
    }
}

// ---------------------------------------------------------------------------
// Reduce split-K partials of x_dbl:
//   dtlow[m][j] = s   for j < 64;   bcT[j-64][m] = s  for j >= 64
// ---------------------------------------------------------------------------
__global__ __launch_bounds__(256) void reduce_xdbl_kernel(
    const float* __restrict__ part, float* __restrict__ dtlow,
    float* __restrict__ bcT)
{
    const int idx = blockIdx.x * 256 + threadIdx.x;
    if (idx >= ML * DXD) return;
    const int m = idx / DXD;
    const int j = idx - m * DXD;
    const float* p = part + (size_t)m * 768 + j;
    float s = 0.0f;
#pragma unroll
    for (int kc = 0; kc < 8; ++kc) s += p[kc * DXD];
    if (j < DTR) dtlow[(size_t)m * DTR + j] = s;
    else         bcT[(size_t)(j - DTR) * ML + m] = s;
}

// ---------------------------------------------------------------------------
// Depthwise causal conv (width 4) + bias + SiLU, TRANSPOSING output:
// reads xc[m][d] tiles (coalesced, +3 halo rows), writes xT[d][m] (coalesced).
// ---------------------------------------------------------------------------
constexpr int CT_LDS = 260;   // LDS row stride (words)
__global__ __launch_bounds__(256) void conv_transpose_kernel(
    const float* __restrict__ xc,
    const float* __restrict__ conv_w,
    const float* __restrict__ conv_b,
    float* __restrict__ xT)
{
    __shared__ float tile[32][CT_LDS];
    const int d0 = blockIdx.x * 32;
    const int m0 = blockIdx.y * 256;
    const int t  = threadIdx.x;
    const bool atStart = ((m0 & (Ls - 1)) == 0);

    // load rows r=-3..255  ->  tile[d][3+r]
    for (int rg = 0; rg < 33; ++rg) {
        const int r = rg * 8 + (t >> 5) - 3;
        const int dcol = t & 31;
        if (r <= 255) {
            float v = 0.0f;
            if (r >= 0 || !atStart)
                v = xc[(size_t)(m0 + r) * DI + d0 + dcol];
            tile[dcol][3 + r] = v;
        }
    }
    __syncthreads();

    const int dd  = t >> 3;
    const int seg = (t & 7) * 32;
    const int d   = d0 + dd;
    const float4 cw = *(const float4*)(conv_w + (d << 2));
    const float  cb = conv_b[d];
    float* dst = xT + (size_t)d * ML + m0 + seg;

    float4 cur = *(const float4*)&tile[dd][seg];
#pragma unroll
    for (int g = 0; g < 8; ++g) {
        const float4 nxt = *(const float4*)&tile[dd][seg + 4 * g + 4];
        const float a0 = cb + cw.x*cur.x + cw.y*cur.y + cw.z*cur.z + cw.w*cur.w;
        const float a1 = cb + cw.x*cur.y + cw.y*cur.z + cw.z*cur.w + cw.w*nxt.x;
        const float a2 = cb + cw.x*cur.z + cw.y*cur.w + cw.z*nxt.x + cw.w*nxt.y;
        const float a3 = cb + cw.x*cur.w + cw.y*nxt.x + cw.z*nxt.y + cw.w*nxt.z;
        float4 o;
        o.x = a0 * sigmoidf_(a0); o.y = a1 * sigmoidf_(a1);
        o.z = a2 * sigmoidf_(a2); o.w = a3 * sigmoidf_(a3);
        *(float4*)(dst + 4 * g) = o;
        cur = nxt;
    }
}

// ---------------------------------------------------------------------------
// Chunked scan pass 1 (chunks 0..NCH-2): per (b,c,d,n) run CHL steps from
// h=0; emit chunk-end state hend and chunk decay exp(Anat*sum(dt)).
// Depth-2 register prefetch (8 steps / 2 float4-iters in flight).
// ---------------------------------------------------------------------------
__global__ __launch_bounds__(256) void scan_pass1(
    const float* __restrict__ dtT,     // [DI][ML]
    const float* __restrict__ xT,      // [DI][ML]
    const float* __restrict__ bcT,     // [32][ML]
    const float* __restrict__ A_log,
    float* __restrict__ hend, float* __restrict__ Dprod)
{
    const int b    = blockIdx.z;
    const int c    = blockIdx.y;
    const int lane = threadIdx.x & 63;
    const int wave = threadIdx.x >> 6;
    const int n    = lane & 15;
    const int dl   = lane >> 4;
    const int d    = blockIdx.x * 16 + wave * 4 + dl;
    const int m0   = b * Ls + c * CHL;

    const float Anat = -__expf(A_log[(d << 4) + n]);

    const float4* dtp = (const float4*)(dtT + (size_t)d * ML + m0);
    const float4* xp  = (const float4*)(xT  + (size_t)d * ML + m0);
    const float4* Bp  = (const float4*)(bcT + (size_t)n * ML + m0);

    float4 dtA = dtp[0], xA = xp[0], BA = Bp[0];
    float4 dtB = dtp[1], xB = xp[1], BB = Bp[1];
    float h = 0.0f, S = 0.0f;

    for (int it = 0; it < CHL / 4; ++it) {
        const float4 dtc = dtA, xc4 = xA, Bc = BA;
        dtA = dtB; xA = xB; BA = BB;
        if (it + 2 < CHL / 4) {
            dtB = dtp[it + 2]; xB = xp[it + 2]; BB = Bp[it + 2];
        }
#pragma unroll
        for (int i = 0; i < 4; ++i) {
            const float dtv = ((const float*)&dtc)[i];
            const float xv  = ((const float*)&xc4)[i];
            const float Bn  = ((const float*)&Bc)[i];
            S += dtv;
            const float e = __expf(dtv * Anat);
            h = fmaf(e, h, dtv * xv * Bn);
        }
    }

    const size_t idx = (((size_t)(b * NCH + c) * DI + d) << 4) + n;
    hend[idx]  = h;
    Dprod[idx] = __expf(Anat * S);
}

// ---------------------------------------------------------------------------
// Chunked scan pass 2: fold h_init inline, run CHL steps, DPP-reduce y over
// n, add x*D. Writes ungated yT IN-PLACE over xT. Depth-2 prefetch.
// ---------------------------------------------------------------------------
__global__ __launch_bounds__(256) void scan_pass2(
    const float* __restrict__ dtT,     // [DI][ML]
    float* xT,                          // in: x, out: yT (in-place)
    const float* __restrict__ bcT,     // [32][ML]
    const float* __restrict__ A_log,
    const float* __restrict__ Dp,
    const float* __restrict__ hend, const float* __restrict__ Dprod)
{
    const int b    = blockIdx.z;
    const int c    = blockIdx.y;
    const int lane = threadIdx.x & 63;
    const int wave = threadIdx.x >> 6;
    const int n    = lane & 15;
    const int dl   = lane >> 4;
    const int d    = blockIdx.x * 16 + wave * 4 + dl;
    const int m0   = b * Ls + c * CHL;

    const float Anat = -__expf(A_log[(d << 4) + n]);
    const float dpd  = Dp[d];

    // fold chunk summaries 0..c-1 -> h_init
    float h = 0.0f;
    for (int cp = 0; cp < c; ++cp) {
        const size_t off = (((size_t)(b * NCH + cp) * DI + d) << 4) + n;
        h = fmaf(Dprod[off], h, hend[off]);
    }

    const float4* dtp = (const float4*)(dtT + (size_t)d * ML + m0);
    const float4* xp  = (const float4*)(xT  + (size_t)d * ML + m0);
    const float4* Bp  = (const float4*)(bcT + (size_t)n * ML + m0);
    const float4* Cp  = (const float4*)(bcT + (size_t)(DST + n) * ML + m0);
    float4* yq = (float4*)(xT + (size_t)d * ML + m0);

    float4 dtA = dtp[0], xA = xp[0], BA = Bp[0], CA = Cp[0];
    float4 dtB = dtp[1], xB = xp[1], BB = Bp[1], CB = Cp[1];

    for (int it = 0; it < CHL / 4; ++it) {
        const float4 dtc = dtA, xc4 = xA, Bc = BA, Cc = CA;
        dtA = dtB; xA = xB; BA = BB; CA = CB;
        if (it + 2 < CHL / 4) {
            dtB = dtp[it + 2]; xB = xp[it + 2];
            BB = Bp[it + 2];   CB = Cp[it + 2];
        }
        float4 y4;
#pragma unroll
        for (int i = 0; i < 4; ++i) {
            const float dtv = ((const float*)&dtc)[i];
            const float xv  = ((const float*)&xc4)[i];
            const float Bn  = ((const float*)&Bc)[i];
            const float Cn  = ((const float*)&Cc)[i];
            const float e = __expf(dtv * Anat);
            h = fmaf(e, h, dtv * xv * Bn);
            const float p = red16_(h * Cn);
            ((float*)&y4)[i] = fmaf(xv, dpd, p);
        }
        if (n == 0) yq[it] = y4;
    }
}

// ---------------------------------------------------------------------------
// Gate + transpose: y_bf16[m][d] = bf16( yT[d][m] * zg[m][d] ).
// ---------------------------------------------------------------------------
__global__ __launch_bounds__(256) void gate_transpose_kernel(
    const float* __restrict__ yT,       // [DI][ML]
    const float* __restrict__ zg,       // [ML][DI]  (silu already applied)
    unsigned short* __restrict__ yb)    // [ML][DI] bf16
{
    __shared__ float Ty[64][65];
    __shared__ float Tz[64][65];
    const int d0 = blockIdx.x * 64;
    const int m0 = blockIdx.y * 64;
    const int t  = threadIdx.x;
    const int cc = t & 63, r4 = t >> 6;

#pragma unroll 4
    for (int rr = 0; rr < 16; ++rr) {
        const int r = rr * 4 + r4;
        Ty[r][cc] = yT[(size_t)(d0 + r) * ML + m0 + cc];
        Tz[r][cc] = zg[(size_t)(m0 + r) * DI + d0 + cc];
    }
    __syncthreads();

    const int dp  = (t & 31) * 2;
    const int mr4 = t >> 5;
#pragma unroll 4
    for (int rr = 0; rr < 8; ++rr) {
        const int mr = rr * 8 + mr4;
        const float v0 = Ty[dp][mr]     * Tz[mr][dp];
        const float v1 = Ty[dp + 1][mr] * Tz[mr][dp + 1];
        *(unsigned int*)(yb + (size_t)(m0 + mr) * DI + d0 + dp) =
            (unsigned int)pk_bf16(v0, v1);
    }
}

// ---------------------------------------------------------------------------
extern "C" void kernel_launch(void* const* d_in, const int* in_sizes, int n_in,
                              void* d_out, int out_size, void* d_ws, size_t ws_size,
                              hipStream_t stream)
{
    const float* x      = (const float*)d_in[0];
    const float* W_in   = (const float*)d_in[1];
    const float* conv_w = (const float*)d_in[2];
    const float* conv_b = (const float*)d_in[3];
    const float* W_x    = (const float*)d_in[4];
    const float* W_dt   = (const float*)d_in[5];
    const float* b_dt   = (const float*)d_in[6];
    const float* A_log  = (const float*)d_in[7];
    const float* Dp     = (const float*)d_in[8];
    const float* W_out  = (const float*)d_in[9];
    float* out = (float*)d_out;

    // workspace (proven 48.75 MB footprint):
    float* ws     = (float*)d_ws;
    float* xc_arr = ws;                         // 16 MB: xc -> splitK part -> dtT -> {ybf 8MB | wobf 4MB}
    float* zg_arr = xc_arr + (size_t)ML * DI;   // 16 MB: silu(z); later outGEMM partials 0-1
    float* xT_arr = zg_arr + (size_t)ML * DI;   // 16 MB: {xbf|wibf} -> xT[d][m] -> yT; later partials 2-3
    float* dtlow  = xT_arr + (size_t)ML * DI;   // 0.5 MB: x_dbl[:, :64]
    float* bcT    = dtlow  + (size_t)ML * DTR;  // 0.25 MB: B/C transposed [32][ML]

    // d_out scratch (dead until out-GEMM reduce): 2 + 2 = 4 MB of 8
    float* hend  = out;                                   // [Bb*NCH*DI*16] 2 MB
    float* Dprod = hend + (size_t)Bb * NCH * DI * DST;    // 2 MB

    // bf16 staging buffers
    unsigned short* xbf  = (unsigned short*)xT_arr;            // 4 MB
    unsigned short* wibf = xbf + (size_t)ML * DM;              // 8 MB
    float* dtT = xc_arr;                                       // [DI][ML]
    unsigned short* ybf  = (unsigned short*)xc_arr;            // 8 MB
    unsigned short* wobf = (unsigned short*)xc_arr + (size_t)ML * DI;  // 4 MB
    float* oPart = zg_arr;   // out-GEMM split-K partials: 4 x 8 MB

    const dim3 blk(256);

    // 0) convert x, W_in to bf16 (into xT region, dead until conv)
    cvt_bf16_kernel<<<dim3(ML * DM / 4 / 256), blk, 0, stream>>>(
        x, xbf, ML * DM / 4);
    cvt_bf16_kernel<<<dim3(DXZ * DM / 4 / 256), blk, 0, stream>>>(
        W_in, wibf, DXZ * DM / 4);

    // 1) in-proj: xc | silu(z) = x @ W_in^T   (bf16 MFMA, BN=64, 1024 blocks)
    gemm_bf16bf16<1, 64><<<dim3(DXZ / 64, ML / 128), blk, 0, stream>>>(
        xbf, DM, wibf, DM, xc_arr, zg_arr, DI, DM, 0, 0, 0);

    // 2) depthwise causal conv + silu, transposed -> xT[d][m]
    conv_transpose_kernel<<<dim3(DI / 32, ML / 256), blk, 0, stream>>>(
        xc_arr, conv_w, conv_b, xT_arr);

    // 3) x_dbl partials = x @ W_x^T from xT (ATRANS, split-K x8) -> xc (dead)
    gemm_nt<0, 1><<<dim3(1, ML / 128, 8), blk, 0, stream>>>(
        xT_arr, ML, W_x, DI, xc_arr, 768, DXD, DI / 8, nullptr,
        (DI / 8) * ML, DI / 8, DXD);
    reduce_xdbl_kernel<<<dim3((ML * DXD + 255) / 256), blk, 0, stream>>>(
        xc_arr, dtlow, bcT);

    // 4) dt_T = softplus(W_dt @ dtlow^T + b_dt[row])  [DI][ML] over xc
    gemm_nt<2, 0><<<dim3(ML / 128, DI / 128), blk, 0, stream>>>(
        W_dt, DTR, dtlow, DTR, dtT, ML, ML, DTR, b_dt, 0, 0, 0);

    // 5) chunked selective scan; pass2 writes ungated yT in-place over xT
    scan_pass1<<<dim3(DI / 16, NCH - 1, Bb), blk, 0, stream>>>(
        dtT, xT_arr, bcT, A_log, hend, Dprod);
    scan_pass2<<<dim3(DI / 16, NCH, Bb), blk, 0, stream>>>(
        dtT, xT_arr, bcT, A_log, Dp, hend, Dprod);

    // 6) gate + transpose -> ybf; convert W_out -> bf16 (dtT dead now)
    gate_transpose_kernel<<<dim3(DI / 64, ML / 64), blk, 0, stream>>>(
        xT_arr, zg_arr, ybf);
    cvt_bf16_kernel<<<dim3(DM * DI / 4 / 256), blk, 0, stream>>>(
        W_out, wobf, DM * DI / 4);

    // 7) out partials = ybf @ wobf^T  (bf16 MFMA, BN=64, split-K x4)
    gemm_bf16bf16<0, 64><<<dim3(DM / 64, ML / 128, 4), blk, 0, stream>>>(
        ybf, DI, wobf, DI, oPart, nullptr, DM, DI / 4,
        DI / 4, DI / 4, (long)ML * DM);

    // 8) out = sum of 4 partials
    reduce4_kernel<<<dim3((ML * DM / 4 + 255) / 256), blk, 0, stream>>>(
        oPart, out, ML * DM / 4);
}